// Round 4
// baseline (296.724 us; speedup 1.0000x reference)
//
#include <hip/hip_runtime.h>

#define K_CODES 1024
#define DIM 64
#define OUT_Q 8388608  // 32*64*64*64 quantized elems; loss at [OUT_Q]; indices at [OUT_Q+1..]
#define NPOS 131072
#define MAXC 12        // shortlist slots per position
#define EPS 2e-3f      // shortlist margin (>=10x the split-bf16 error bound)

typedef float v2 __attribute__((ext_vector_type(2)));
typedef float f32x4 __attribute__((ext_vector_type(4)));
typedef short bf16x8 __attribute__((ext_vector_type(8)));

#if __has_builtin(__builtin_elementwise_fma)
#define FMA2(a, b, c) __builtin_elementwise_fma((a), (b), (c))
#else
static __device__ inline v2 FMA2(v2 a, v2 b, v2 c) {
    v2 r; r.x = fmaf(a.x, b.x, c.x); r.y = fmaf(a.y, b.y, c.y); return r;
}
#endif

static __device__ inline unsigned short f2bf(float f) {  // RNE f32->bf16 (normal values)
    union { float f; unsigned u; } c; c.f = f;
    unsigned u = c.u;
    u += 0x7fffu + ((u >> 16) & 1u);
    return (unsigned short)(u >> 16);
}
static __device__ inline float bf2f(unsigned short h) {
    union { unsigned u; float f; } c; c.u = ((unsigned)h) << 16;
    return c.f;
}

// ---- pass 1: ee[k] (exact, same chain as before) + bf16 hi/lo split of E ----
__global__ void vq_prep(const float* __restrict__ emb, float* __restrict__ ee,
                        unsigned short* __restrict__ Ehi, unsigned short* __restrict__ Elo) {
    int k = blockIdx.x * blockDim.x + threadIdx.x;
    if (k < K_CODES) {
        float s = 0.f;
        #pragma unroll
        for (int d = 0; d < DIM; ++d) {
            float vv = emb[k * DIM + d];
            s = fmaf(vv, vv, s);
            unsigned short hh = f2bf(vv);
            Ehi[k * DIM + d] = hh;
            Elo[k * DIM + d] = f2bf(vv - bf2f(hh));
        }
        ee[k] = s;
    }
}

// ---- pass 2: MFMA approx distances, per-lane best2, margin shortlist ----
__global__ __launch_bounds__(256, 4) void vq_dist_mfma(
        const float* __restrict__ in, const unsigned short* __restrict__ Ehi,
        const unsigned short* __restrict__ Elo, const float* __restrict__ ee,
        unsigned short* __restrict__ cand, int* __restrict__ cnt) {
    const int t = threadIdx.x;
    const int wv = t >> 6;
    const int l = t & 63;
    const int n_base = blockIdx.x * 64;  // 64 positions = one (b,h) row of w
    // element offset of in[b][0][h][w=0]
    const size_t ibase = ((size_t)(n_base >> 12) << 18) + ((size_t)((n_base >> 6) & 63) << 6);

    // ---- A fragments: 16 positions x 64 dims, split hi/lo, 2 K-halves ----
    // A layout (16x16x32): row = l&15, k = (l>>4)*8 + j
    const int pos = wv * 16 + (l & 15);
    const int dbase = (l >> 4) * 8;
    bf16x8 XH0, XL0, XH1, XL1;
    #pragma unroll
    for (int j = 0; j < 8; ++j) {
        float v0 = in[ibase + ((size_t)(dbase + j) << 12) + pos];
        float v1 = in[ibase + ((size_t)(32 + dbase + j) << 12) + pos];
        unsigned short h0 = f2bf(v0), h1 = f2bf(v1);
        XH0[j] = (short)h0; XL0[j] = (short)f2bf(v0 - bf2f(h0));
        XH1[j] = (short)h1; XL1[j] = (short)f2bf(v1 - bf2f(h1));
    }

    // per-lane best2 for 4 rows (C layout: col=l&15, row=(l>>4)*4+reg)
    float d1[4], d2[4];
    int k1[4], k2[4];
    #pragma unroll
    for (int j = 0; j < 4; ++j) { d1[j] = 3.4e38f; d2[j] = 3.4e38f; k1[j] = 0; k2[j] = 0; }

    // B layout (16x16x32): col = l&15, k = (l>>4)*8 + j  -> 8 contiguous dims of code col
    const unsigned short* pEh = Ehi + ((size_t)(l & 15) * DIM) + dbase;
    const unsigned short* pEl = Elo + ((size_t)(l & 15) * DIM) + dbase;
    const float* pee = ee + (l & 15);

    #pragma unroll 2
    for (int kt = 0; kt < 64; ++kt) {
        bf16x8 BH0 = *(const bf16x8*)(pEh);
        bf16x8 BH1 = *(const bf16x8*)(pEh + 32);
        bf16x8 BL0 = *(const bf16x8*)(pEl);
        bf16x8 BL1 = *(const bf16x8*)(pEl + 32);
        float eec = *pee;
        pEh += 16 * DIM; pEl += 16 * DIM; pee += 16;

        f32x4 z = {0.f, 0.f, 0.f, 0.f};
        f32x4 a0 = __builtin_amdgcn_mfma_f32_16x16x32_bf16(XH0, BH0, z, 0, 0, 0);
        f32x4 a1 = __builtin_amdgcn_mfma_f32_16x16x32_bf16(XH1, BH1, z, 0, 0, 0);
        a0 = __builtin_amdgcn_mfma_f32_16x16x32_bf16(XH0, BL0, a0, 0, 0, 0);
        a1 = __builtin_amdgcn_mfma_f32_16x16x32_bf16(XH1, BL1, a1, 0, 0, 0);
        a0 = __builtin_amdgcn_mfma_f32_16x16x32_bf16(XL0, BH0, a0, 0, 0, 0);
        a1 = __builtin_amdgcn_mfma_f32_16x16x32_bf16(XL1, BH1, a1, 0, 0, 0);

        const int c = kt * 16 + (l & 15);
        #pragma unroll
        for (int j = 0; j < 4; ++j) {
            float dd = fmaf(-2.f, a0[j] + a1[j], eec);
            bool c1 = dd < d1[j];
            bool c2 = dd < d2[j];
            k2[j] = c1 ? k1[j] : (c2 ? c : k2[j]);
            d2[j] = c1 ? d1[j] : (c2 ? dd : d2[j]);
            k1[j] = c1 ? c : k1[j];
            d1[j] = c1 ? dd : d1[j];
        }
    }

    // ---- shortlist: all lane-candidates within EPS of the row's approx min ----
    const int g = l >> 4;
    const int li = l & 15;
    #pragma unroll
    for (int j = 0; j < 4; ++j) {
        float m = d1[j];
        m = fminf(m, __shfl_xor(m, 1, 64));
        m = fminf(m, __shfl_xor(m, 2, 64));
        m = fminf(m, __shfl_xor(m, 4, 64));
        m = fminf(m, __shfl_xor(m, 8, 64));
        const float thr = m + EPS;
        bool f1 = d1[j] <= thr;
        bool f2 = d2[j] <= thr;
        unsigned long long b1 = __ballot(f1);
        unsigned long long b2 = __ballot(f2);
        unsigned fld1 = (unsigned)((b1 >> (g * 16)) & 0xFFFFull);
        unsigned fld2 = (unsigned)((b2 >> (g * 16)) & 0xFFFFull);
        int c1n = __popc(fld1);
        int pre1 = __popc(fld1 & ((1u << li) - 1u));
        int pre2 = c1n + __popc(fld2 & ((1u << li) - 1u));
        const int n_row = n_base + wv * 16 + g * 4 + j;
        if (f1 && pre1 < MAXC) cand[n_row * MAXC + pre1] = (unsigned short)k1[j];
        if (f2 && pre2 < MAXC) cand[n_row * MAXC + pre2] = (unsigned short)k2[j];
        if (li == 0) {
            int tot = c1n + __popc(fld2);
            cnt[n_row] = tot < MAXC ? tot : MAXC;
        }
    }
}

// ---- pass 3: exact f32 recheck of shortlist + gather + write + loss ----
__global__ __launch_bounds__(256) void vq_pick(
        const float* __restrict__ in, const float* __restrict__ emb,
        const float* __restrict__ ee, const unsigned short* __restrict__ cand,
        const int* __restrict__ cnt, float* __restrict__ out,
        float* __restrict__ partials) {
    const int n = blockIdx.x * 256 + threadIdx.x;
    const int w = n & 63;
    const int h = (n >> 6) & 63;
    const int b = n >> 12;
    const size_t base = ((size_t)b << 18) + ((size_t)h << 6) + (size_t)w;

    v2 x[32];
    #pragma unroll
    for (int d = 0; d < 32; ++d) {
        x[d].x = in[base + ((size_t)(2 * d + 0) << 12)];
        x[d].y = in[base + ((size_t)(2 * d + 1) << 12)];
    }
    asm volatile("" : "+v"(x[0]), "+v"(x[1]), "+v"(x[2]), "+v"(x[3]),
                      "+v"(x[4]), "+v"(x[5]), "+v"(x[6]), "+v"(x[7]),
                      "+v"(x[8]), "+v"(x[9]), "+v"(x[10]), "+v"(x[11]),
                      "+v"(x[12]), "+v"(x[13]), "+v"(x[14]), "+v"(x[15]));
    asm volatile("" : "+v"(x[16]), "+v"(x[17]), "+v"(x[18]), "+v"(x[19]),
                      "+v"(x[20]), "+v"(x[21]), "+v"(x[22]), "+v"(x[23]),
                      "+v"(x[24]), "+v"(x[25]), "+v"(x[26]), "+v"(x[27]),
                      "+v"(x[28]), "+v"(x[29]), "+v"(x[30]), "+v"(x[31]));

    // exact f32 distance for each shortlisted code -- bit-identical to R3's scan
    const int c0 = cnt[n];
    float bestD = 3.4e38f;
    int bestK = 0x7FFFFFFF;
    for (int s = 0; s < c0; ++s) {
        const int k = (int)cand[n * MAXC + s];
        const v2* __restrict__ e = (const v2*)(emb + (size_t)k * DIM);
        v2 a0 = {0.f, 0.f}, a1 = {0.f, 0.f}, a2 = {0.f, 0.f}, a3 = {0.f, 0.f};
        #pragma unroll
        for (int d = 0; d < 32; d += 4) {
            a0 = FMA2(x[d + 0], e[d + 0], a0);
            a1 = FMA2(x[d + 1], e[d + 1], a1);
            a2 = FMA2(x[d + 2], e[d + 2], a2);
            a3 = FMA2(x[d + 3], e[d + 3], a3);
        }
        v2 s2 = (a0 + a1) + (a2 + a3);
        float dk = fmaf(-2.f, s2.x + s2.y, ee[k]);
        // lexicographic (dist, k) min == ascending-k strict-< first occurrence
        if (dk < bestD || (dk == bestD && k < bestK)) { bestD = dk; bestK = k; }
    }
    out[OUT_Q + 1 + n] = (float)bestK;

    const v2* __restrict__ eq = (const v2*)(emb + (size_t)bestK * DIM);
    v2 errs2 = {0.f, 0.f};
    #pragma unroll
    for (int d = 0; d < 32; ++d) {
        v2 q = eq[d];
        v2 diff = q - x[d];
        errs2 = FMA2(diff, diff, errs2);
        out[base + ((size_t)(2 * d + 0) << 12)] = q.x;
        out[base + ((size_t)(2 * d + 1) << 12)] = q.y;
    }
    float errs = errs2.x + errs2.y;

    #pragma unroll
    for (int off = 32; off > 0; off >>= 1) errs += __shfl_xor(errs, off, 64);

    __shared__ float red[4];
    const int wave = threadIdx.x >> 6;
    const int lane = threadIdx.x & 63;
    if (lane == 0) red[wave] = errs;
    __syncthreads();
    if (threadIdx.x == 0) {
        partials[blockIdx.x] = (red[0] + red[1]) + (red[2] + red[3]);
    }
}

// ---- pass 4: deterministic final loss reduction ----
__global__ void vq_loss(const float* __restrict__ partials, float* __restrict__ out) {
    if (threadIdx.x == 0 && blockIdx.x == 0) {
        float s = 0.f;
        for (int i = 0; i < 512; ++i) s += partials[i];
        out[OUT_Q] = s * (float)(1.25 / 8388608.0);  // q_loss + 0.25*e_loss
    }
}

extern "C" void kernel_launch(void* const* d_in, const int* in_sizes, int n_in,
                              void* d_out, int out_size, void* d_ws, size_t ws_size,
                              hipStream_t stream) {
    const float* in  = (const float*)d_in[0];   // [32,64,64,64] f32
    const float* emb = (const float*)d_in[1];   // [1024,64] f32
    float* out = (float*)d_out;

    // ws layout (bytes): ee f32[1024] | Ehi u16[64K] | Elo u16[64K] |
    //                    cand u16[NPOS*12] | cnt i32[NPOS] | partials f32[512]
    char* w = (char*)d_ws;
    float* ee = (float*)w;                                   w += K_CODES * 4;
    unsigned short* Ehi = (unsigned short*)w;                w += K_CODES * DIM * 2;
    unsigned short* Elo = (unsigned short*)w;                w += K_CODES * DIM * 2;
    unsigned short* cand = (unsigned short*)w;               w += (size_t)NPOS * MAXC * 2;
    int* cnt = (int*)w;                                      w += (size_t)NPOS * 4;
    float* partials = (float*)w;

    vq_prep<<<4, 256, 0, stream>>>(emb, ee, Ehi, Elo);
    vq_dist_mfma<<<2048, 256, 0, stream>>>(in, Ehi, Elo, ee, cand, cnt);
    vq_pick<<<512, 256, 0, stream>>>(in, emb, ee, cand, cnt, out, partials);
    vq_loss<<<1, 64, 0, stream>>>(partials, out);
}

// Round 5
// 120.992 us; speedup vs baseline: 2.4524x; 2.4524x over previous
//
#include <hip/hip_runtime.h>

#define K_CODES 1024
#define DIM 64
#define OUT_Q 8388608  // 32*64*64*64 quantized elems; loss at [OUT_Q]; indices at [OUT_Q+1..]
#define NPOS 131072
#define MAXC 12        // shortlist slots per position
#define EPS 2e-3f      // shortlist margin (>=10x the split-bf16 error bound)

typedef float v2 __attribute__((ext_vector_type(2)));
typedef float f32x4 __attribute__((ext_vector_type(4)));
typedef short bf16x8 __attribute__((ext_vector_type(8)));

#if __has_builtin(__builtin_elementwise_fma)
#define FMA2(a, b, c) __builtin_elementwise_fma((a), (b), (c))
#else
static __device__ inline v2 FMA2(v2 a, v2 b, v2 c) {
    v2 r; r.x = fmaf(a.x, b.x, c.x); r.y = fmaf(a.y, b.y, c.y); return r;
}
#endif

static __device__ inline unsigned short f2bf(float f) {  // RNE f32->bf16
    union { float f; unsigned u; } c; c.f = f;
    unsigned u = c.u;
    u += 0x7fffu + ((u >> 16) & 1u);
    return (unsigned short)(u >> 16);
}
static __device__ inline float bf2f(unsigned short h) {
    union { unsigned u; float f; } c; c.u = ((unsigned)h) << 16;
    return c.f;
}

// ---- pass 1: exact ee[k] + prepacked B fragments (coalesced stream layout) ----
// Bpack[kt][chunk][lane][j]: chunk 0/1 = hi half0/half1, chunk 2/3 = lo half0/half1.
// B-frag layout for mfma_16x16x32: lane l supplies B[kdim=(l>>4)*8+j][col=l&15].
__global__ void vq_prep(const float* __restrict__ emb, float* __restrict__ ee,
                        unsigned short* __restrict__ Bpack) {
    int k = blockIdx.x * blockDim.x + threadIdx.x;
    if (k < K_CODES) {
        const int kt = k >> 4, col = k & 15;
        float s = 0.f;
        #pragma unroll
        for (int d = 0; d < DIM; ++d) {
            float vv = emb[k * DIM + d];
            s = fmaf(vv, vv, s);
            unsigned short hh = f2bf(vv);
            unsigned short ll = f2bf(vv - bf2f(hh));
            const int half = d >> 5;
            const int lane = ((d >> 3) & 3) * 16 + col;
            const int j = d & 7;
            Bpack[kt * 2048 + half * 512 + lane * 8 + j] = hh;
            Bpack[kt * 2048 + (2 + half) * 512 + lane * 8 + j] = ll;
        }
        ee[k] = s;
    }
}

// ---- pass 2: MFMA approx distances (coalesced Bpack stream, prefetch-1) ----
__global__ __launch_bounds__(256, 4) void vq_dist_mfma(
        const float* __restrict__ in, const unsigned short* __restrict__ Bpack,
        const float* __restrict__ ee,
        unsigned short* __restrict__ cand, int* __restrict__ cnt) {
    const int t = threadIdx.x;
    const int wv = t >> 6;
    const int l = t & 63;
    const int n_base = blockIdx.x * 64;  // 64 positions = one (b,h) row of w
    const size_t ibase = ((size_t)(n_base >> 12) << 18) + ((size_t)((n_base >> 6) & 63) << 6);

    // ---- A fragments: 16 positions x 64 dims, hi/lo split, 2 K-halves ----
    // A layout (16x16x32): row = l&15, kdim = (l>>4)*8 + j
    const int pos = wv * 16 + (l & 15);
    const int dbase = (l >> 4) * 8;
    bf16x8 XH0, XL0, XH1, XL1;
    #pragma unroll
    for (int j = 0; j < 8; ++j) {
        float v0 = in[ibase + ((size_t)(dbase + j) << 12) + pos];
        float v1 = in[ibase + ((size_t)(32 + dbase + j) << 12) + pos];
        unsigned short h0 = f2bf(v0), h1 = f2bf(v1);
        XH0[j] = (short)h0; XL0[j] = (short)f2bf(v0 - bf2f(h0));
        XH1[j] = (short)h1; XL1[j] = (short)f2bf(v1 - bf2f(h1));
    }

    float d1[4], d2[4];
    int k1[4], k2[4];
    #pragma unroll
    for (int j = 0; j < 4; ++j) { d1[j] = 3.4e38f; d2[j] = 3.4e38f; k1[j] = 0; k2[j] = 0; }

    // coalesced per-lane stream base (lane l's 16B at +l*16 within each 1KB chunk)
    const unsigned short* bp = Bpack + (size_t)l * 8;
    const int li = l & 15;

    bf16x8 BH0 = *(const bf16x8*)(bp + 0);
    bf16x8 BH1 = *(const bf16x8*)(bp + 512);
    bf16x8 BL0 = *(const bf16x8*)(bp + 1024);
    bf16x8 BL1 = *(const bf16x8*)(bp + 1536);
    float eec = ee[li];

    for (int kt = 0; kt < 64; ++kt) {
        // prefetch kt+1 (Bpack & ee padded by one tile: last prefetch reads pad)
        const unsigned short* np = bp + (kt + 1) * 2048;
        bf16x8 nBH0 = *(const bf16x8*)(np + 0);
        bf16x8 nBH1 = *(const bf16x8*)(np + 512);
        bf16x8 nBL0 = *(const bf16x8*)(np + 1024);
        bf16x8 nBL1 = *(const bf16x8*)(np + 1536);
        float neec = ee[(kt + 1) * 16 + li];

        f32x4 z = {0.f, 0.f, 0.f, 0.f};
        f32x4 a0 = __builtin_amdgcn_mfma_f32_16x16x32_bf16(XH0, BH0, z, 0, 0, 0);
        f32x4 a1 = __builtin_amdgcn_mfma_f32_16x16x32_bf16(XH1, BH1, z, 0, 0, 0);
        a0 = __builtin_amdgcn_mfma_f32_16x16x32_bf16(XH0, BL0, a0, 0, 0, 0);
        a1 = __builtin_amdgcn_mfma_f32_16x16x32_bf16(XH1, BL1, a1, 0, 0, 0);
        a0 = __builtin_amdgcn_mfma_f32_16x16x32_bf16(XL0, BH0, a0, 0, 0, 0);
        a1 = __builtin_amdgcn_mfma_f32_16x16x32_bf16(XL1, BH1, a1, 0, 0, 0);

        const int c = kt * 16 + li;
        #pragma unroll
        for (int j = 0; j < 4; ++j) {
            float dd = fmaf(-2.f, a0[j] + a1[j], eec);
            bool c1 = dd < d1[j];
            bool c2 = dd < d2[j];
            k2[j] = c1 ? k1[j] : (c2 ? c : k2[j]);
            d2[j] = c1 ? d1[j] : (c2 ? dd : d2[j]);
            k1[j] = c1 ? c : k1[j];
            d1[j] = c1 ? dd : d1[j];
        }
        BH0 = nBH0; BH1 = nBH1; BL0 = nBL0; BL1 = nBL1; eec = neec;
    }

    // ---- shortlist: all lane-candidates within EPS of the row's approx min ----
    const int g = l >> 4;
    #pragma unroll
    for (int j = 0; j < 4; ++j) {
        float m = d1[j];
        m = fminf(m, __shfl_xor(m, 1, 64));
        m = fminf(m, __shfl_xor(m, 2, 64));
        m = fminf(m, __shfl_xor(m, 4, 64));
        m = fminf(m, __shfl_xor(m, 8, 64));
        const float thr = m + EPS;
        bool f1 = d1[j] <= thr;
        bool f2 = d2[j] <= thr;
        unsigned long long b1 = __ballot(f1);
        unsigned long long b2 = __ballot(f2);
        unsigned fld1 = (unsigned)((b1 >> (g * 16)) & 0xFFFFull);
        unsigned fld2 = (unsigned)((b2 >> (g * 16)) & 0xFFFFull);
        int c1n = __popc(fld1);
        int pre1 = __popc(fld1 & ((1u << li) - 1u));
        int pre2 = c1n + __popc(fld2 & ((1u << li) - 1u));
        const int n_row = n_base + wv * 16 + g * 4 + j;
        if (f1 && pre1 < MAXC) cand[n_row * MAXC + pre1] = (unsigned short)k1[j];
        if (f2 && pre2 < MAXC) cand[n_row * MAXC + pre2] = (unsigned short)k2[j];
        if (li == 0) {
            int tot = c1n + __popc(fld2);
            cnt[n_row] = tot < MAXC ? tot : MAXC;
        }
    }
}

// ---- pass 3: exact f32 recheck of shortlist + gather + write + loss ----
__global__ __launch_bounds__(256) void vq_pick(
        const float* __restrict__ in, const float* __restrict__ emb,
        const float* __restrict__ ee, const unsigned short* __restrict__ cand,
        const int* __restrict__ cnt, float* __restrict__ out,
        float* __restrict__ partials) {
    const int n = blockIdx.x * 256 + threadIdx.x;
    const int w = n & 63;
    const int h = (n >> 6) & 63;
    const int b = n >> 12;
    const size_t base = ((size_t)b << 18) + ((size_t)h << 6) + (size_t)w;

    v2 x[32];
    #pragma unroll
    for (int d = 0; d < 32; ++d) {
        x[d].x = in[base + ((size_t)(2 * d + 0) << 12)];
        x[d].y = in[base + ((size_t)(2 * d + 1) << 12)];
    }
    asm volatile("" : "+v"(x[0]), "+v"(x[1]), "+v"(x[2]), "+v"(x[3]),
                      "+v"(x[4]), "+v"(x[5]), "+v"(x[6]), "+v"(x[7]),
                      "+v"(x[8]), "+v"(x[9]), "+v"(x[10]), "+v"(x[11]),
                      "+v"(x[12]), "+v"(x[13]), "+v"(x[14]), "+v"(x[15]));
    asm volatile("" : "+v"(x[16]), "+v"(x[17]), "+v"(x[18]), "+v"(x[19]),
                      "+v"(x[20]), "+v"(x[21]), "+v"(x[22]), "+v"(x[23]),
                      "+v"(x[24]), "+v"(x[25]), "+v"(x[26]), "+v"(x[27]),
                      "+v"(x[28]), "+v"(x[29]), "+v"(x[30]), "+v"(x[31]));

    // exact f32 distance for each shortlisted code -- bit-identical to R3's scan
    const int c0 = cnt[n];
    float bestD = 3.4e38f;
    int bestK = 0x7FFFFFFF;
    for (int s = 0; s < c0; ++s) {
        const int k = (int)cand[n * MAXC + s];
        const v2* __restrict__ e = (const v2*)(emb + (size_t)k * DIM);
        v2 a0 = {0.f, 0.f}, a1 = {0.f, 0.f}, a2 = {0.f, 0.f}, a3 = {0.f, 0.f};
        #pragma unroll
        for (int d = 0; d < 32; d += 4) {
            a0 = FMA2(x[d + 0], e[d + 0], a0);
            a1 = FMA2(x[d + 1], e[d + 1], a1);
            a2 = FMA2(x[d + 2], e[d + 2], a2);
            a3 = FMA2(x[d + 3], e[d + 3], a3);
        }
        v2 s2 = (a0 + a1) + (a2 + a3);
        float dk = fmaf(-2.f, s2.x + s2.y, ee[k]);
        // lexicographic (dist, k) min == ascending-k strict-< first occurrence
        if (dk < bestD || (dk == bestD && k < bestK)) { bestD = dk; bestK = k; }
    }
    out[OUT_Q + 1 + n] = (float)bestK;

    const v2* __restrict__ eq = (const v2*)(emb + (size_t)bestK * DIM);
    v2 errs2 = {0.f, 0.f};
    #pragma unroll
    for (int d = 0; d < 32; ++d) {
        v2 q = eq[d];
        v2 diff = q - x[d];
        errs2 = FMA2(diff, diff, errs2);
        out[base + ((size_t)(2 * d + 0) << 12)] = q.x;
        out[base + ((size_t)(2 * d + 1) << 12)] = q.y;
    }
    float errs = errs2.x + errs2.y;

    #pragma unroll
    for (int off = 32; off > 0; off >>= 1) errs += __shfl_xor(errs, off, 64);

    __shared__ float red[4];
    const int wave = threadIdx.x >> 6;
    const int lane = threadIdx.x & 63;
    if (lane == 0) red[wave] = errs;
    __syncthreads();
    if (threadIdx.x == 0) {
        partials[blockIdx.x] = (red[0] + red[1]) + (red[2] + red[3]);
    }
}

// ---- pass 4: deterministic final loss reduction ----
__global__ void vq_loss(const float* __restrict__ partials, float* __restrict__ out) {
    if (threadIdx.x == 0 && blockIdx.x == 0) {
        float s = 0.f;
        for (int i = 0; i < 512; ++i) s += partials[i];
        out[OUT_Q] = s * (float)(1.25 / 8388608.0);  // q_loss + 0.25*e_loss
    }
}

extern "C" void kernel_launch(void* const* d_in, const int* in_sizes, int n_in,
                              void* d_out, int out_size, void* d_ws, size_t ws_size,
                              hipStream_t stream) {
    const float* in  = (const float*)d_in[0];   // [32,64,64,64] f32
    const float* emb = (const float*)d_in[1];   // [1024,64] f32
    float* out = (float*)d_out;

    // ws layout (bytes): ee f32[1024+16 pad] | Bpack u16[(64+1)*2048 pad] |
    //                    cand u16[NPOS*12] | cnt i32[NPOS] | partials f32[512]
    char* w = (char*)d_ws;
    float* ee = (float*)w;                    w += (K_CODES + 16) * 4;
    unsigned short* Bpack = (unsigned short*)w; w += (size_t)65 * 2048 * 2;
    unsigned short* cand = (unsigned short*)w;  w += (size_t)NPOS * MAXC * 2;
    int* cnt = (int*)w;                         w += (size_t)NPOS * 4;
    float* partials = (float*)w;

    vq_prep<<<4, 256, 0, stream>>>(emb, ee, Bpack);
    vq_dist_mfma<<<2048, 256, 0, stream>>>(in, Bpack, ee, cand, cnt);
    vq_pick<<<512, 256, 0, stream>>>(in, emb, ee, cand, cnt, out, partials);
    vq_loss<<<1, 64, 0, stream>>>(partials, out);
}

// Round 7
// 107.812 us; speedup vs baseline: 2.7522x; 1.1223x over previous
//
#include <hip/hip_runtime.h>

#define K_CODES 1024
#define DIM 64
#define OUT_Q 8388608  // 32*64*64*64 quantized elems; loss at [OUT_Q]; indices at [OUT_Q+1..]
#define NPOS 131072
#define MAXC 12        // shortlist slots per position
#define EPS 4e-3f      // shortlist margin (>=5x worst-case pack+approx skew ~7e-4)
#define BIAS 32.0f     // makes packed distances positive (|2*dot| <= ~26 < 32)

typedef float v2 __attribute__((ext_vector_type(2)));
typedef float f32x4 __attribute__((ext_vector_type(4)));
typedef short bf16x8 __attribute__((ext_vector_type(8)));

#if __has_builtin(__builtin_elementwise_fma)
#define FMA2(a, b, c) __builtin_elementwise_fma((a), (b), (c))
#else
static __device__ inline v2 FMA2(v2 a, v2 b, v2 c) {
    v2 r; r.x = fmaf(a.x, b.x, c.x); r.y = fmaf(a.y, b.y, c.y); return r;
}
#endif

static __device__ inline unsigned short f2bf(float f) {  // RNE f32->bf16
    union { float f; unsigned u; } c; c.f = f;
    unsigned u = c.u;
    u += 0x7fffu + ((u >> 16) & 1u);
    return (unsigned short)(u >> 16);
}
static __device__ inline float bf2f(unsigned short h) {
    union { unsigned u; float f; } c; c.u = ((unsigned)h) << 16;
    return c.f;
}

// ---- pass 1: exact ee[k], biased eeb[k], prepacked B fragments ----
// Bpack[kt][chunk][lane][j]: chunk 0/1 = hi half0/half1, chunk 2/3 = lo half0/half1.
// B-frag layout for mfma_16x16x32: lane l supplies B[kdim=(l>>4)*8+j][col=l&15].
__global__ void vq_prep(const float* __restrict__ emb, float* __restrict__ ee,
                        float* __restrict__ eeb, unsigned short* __restrict__ Bpack) {
    int k = blockIdx.x * blockDim.x + threadIdx.x;
    if (k < K_CODES) {
        const int kt = k >> 4, col = k & 15;
        float s = 0.f;
        #pragma unroll
        for (int d = 0; d < DIM; ++d) {
            float vv = emb[k * DIM + d];
            s = fmaf(vv, vv, s);
            unsigned short hh = f2bf(vv);
            unsigned short ll = f2bf(vv - bf2f(hh));
            const int half = d >> 5;
            const int lane = ((d >> 3) & 3) * 16 + col;
            const int j = d & 7;
            Bpack[kt * 2048 + half * 512 + lane * 8 + j] = hh;
            Bpack[kt * 2048 + (2 + half) * 512 + lane * 8 + j] = ll;
        }
        ee[k] = s;          // exact (recheck path)
        eeb[k] = s + BIAS;  // biased (approx path)
    }
}

// one 16x16 tile: 6 chained MFMAs + packed best-2 update (5-bit class-local idx)
#define TILE(BH0, BH1, BL0, BL1, EEC, IDX, U1, U2)                             \
    {                                                                          \
        f32x4 acc = {0.f, 0.f, 0.f, 0.f};                                      \
        acc = __builtin_amdgcn_mfma_f32_16x16x32_bf16(XH0, BH0, acc, 0, 0, 0); \
        acc = __builtin_amdgcn_mfma_f32_16x16x32_bf16(XH0, BL0, acc, 0, 0, 0); \
        acc = __builtin_amdgcn_mfma_f32_16x16x32_bf16(XL0, BH0, acc, 0, 0, 0); \
        acc = __builtin_amdgcn_mfma_f32_16x16x32_bf16(XH1, BH1, acc, 0, 0, 0); \
        acc = __builtin_amdgcn_mfma_f32_16x16x32_bf16(XH1, BL1, acc, 0, 0, 0); \
        acc = __builtin_amdgcn_mfma_f32_16x16x32_bf16(XL1, BH1, acc, 0, 0, 0); \
        _Pragma("unroll")                                                      \
        for (int j = 0; j < 4; ++j) {                                          \
            float dd = fmaf(-2.f, acc[j], EEC);                                \
            unsigned uu = (__float_as_uint(dd) & 0xFFFFFFE0u) | (IDX);         \
            bool lt1 = uu < U1[j];                                             \
            unsigned t2 = uu < U2[j] ? uu : U2[j];                             \
            U2[j] = lt1 ? U1[j] : t2;                                          \
            U1[j] = lt1 ? uu : U1[j];                                          \
        }                                                                      \
    }

// ---- pass 2: MFMA approx distances, packed best-2 per (lane,parity,row) ----
__global__ __launch_bounds__(256, 4) void vq_dist_mfma(
        const float* __restrict__ in, const unsigned short* __restrict__ Bpack,
        const float* __restrict__ eeb,
        unsigned short* __restrict__ cand, int* __restrict__ cnt) {
    const int t = threadIdx.x;
    const int wv = t >> 6;
    const int l = t & 63;
    const int li = l & 15;
    const int n_base = blockIdx.x * 64;  // 64 positions = one (b,h) row of w
    const size_t ibase = ((size_t)(n_base >> 12) << 18) + ((size_t)((n_base >> 6) & 63) << 6);

    // ---- A fragments: 16 positions x 64 dims, hi/lo split, 2 K-halves ----
    // A layout (16x16x32): row = l&15, kdim = (l>>4)*8 + j
    const int pos = wv * 16 + li;
    const int dbase = (l >> 4) * 8;
    bf16x8 XH0, XL0, XH1, XL1;
    #pragma unroll
    for (int j = 0; j < 8; ++j) {
        float v0 = in[ibase + ((size_t)(dbase + j) << 12) + pos];
        float v1 = in[ibase + ((size_t)(32 + dbase + j) << 12) + pos];
        unsigned short h0 = f2bf(v0), h1 = f2bf(v1);
        XH0[j] = (short)h0; XL0[j] = (short)f2bf(v0 - bf2f(h0));
        XH1[j] = (short)h1; XL1[j] = (short)f2bf(v1 - bf2f(h1));
    }
    asm volatile("" : "+v"(XH0), "+v"(XL0), "+v"(XH1), "+v"(XL1));

    unsigned uE1[4] = {0xFFFFFFFFu, 0xFFFFFFFFu, 0xFFFFFFFFu, 0xFFFFFFFFu};
    unsigned uE2[4] = {0xFFFFFFFFu, 0xFFFFFFFFu, 0xFFFFFFFFu, 0xFFFFFFFFu};
    unsigned uO1[4] = {0xFFFFFFFFu, 0xFFFFFFFFu, 0xFFFFFFFFu, 0xFFFFFFFFu};
    unsigned uO2[4] = {0xFFFFFFFFu, 0xFFFFFFFFu, 0xFFFFFFFFu, 0xFFFFFFFFu};

    // coalesced per-lane stream base (lane l's 16B at +l*16 within each 1KB chunk)
    const unsigned short* bp = Bpack + (size_t)l * 8;

    // preload tile 0 into set A
    bf16x8 h0A = *(const bf16x8*)(bp + 0);
    bf16x8 h1A = *(const bf16x8*)(bp + 512);
    bf16x8 l0A = *(const bf16x8*)(bp + 1024);
    bf16x8 l1A = *(const bf16x8*)(bp + 1536);
    float eA = eeb[li];
    unsigned cE = 0, cO = 0;  // class-local tile index (5 bits)

    for (int kt = 0; kt < 64; kt += 2) {
        // prefetch odd tile into set B
        const unsigned short* p1 = bp + (size_t)(kt + 1) * 2048;
        bf16x8 h0B = *(const bf16x8*)(p1 + 0);
        bf16x8 h1B = *(const bf16x8*)(p1 + 512);
        bf16x8 l0B = *(const bf16x8*)(p1 + 1024);
        bf16x8 l1B = *(const bf16x8*)(p1 + 1536);
        float eB = eeb[(kt + 1) * 16 + li];

        TILE(h0A, h1A, l0A, l1A, eA, cE, uE1, uE2);
        ++cE;

        // prefetch next even tile into set A (Bpack/eeb padded: safe at kt=62)
        const unsigned short* p2 = bp + (size_t)(kt + 2) * 2048;
        h0A = *(const bf16x8*)(p2 + 0);
        h1A = *(const bf16x8*)(p2 + 512);
        l0A = *(const bf16x8*)(p2 + 1024);
        l1A = *(const bf16x8*)(p2 + 1536);
        eA = eeb[(kt + 2) * 16 + li];

        TILE(h0B, h1B, l0B, l1B, eB, cO, uO1, uO2);
        ++cO;
    }

    // ---- shortlist: candidates within EPS of the row's approx min ----
    // k reconstruction: even class k = idx*32 + li ; odd class k = idx*32 + 16 + li
    const int g = l >> 4;
    #pragma unroll
    for (int j = 0; j < 4; ++j) {
        unsigned um = uE1[j] < uO1[j] ? uE1[j] : uO1[j];  // U1 <= U2 always
        #pragma unroll
        for (int m = 1; m < 16; m <<= 1) {
            unsigned o = (unsigned)__shfl_xor((int)um, m, 64);
            um = um < o ? um : o;
        }
        const float thr = __uint_as_float(um & 0xFFFFFFE0u) + EPS;
        // NaN-safe: untouched 0xFFFFFFFF unpacks to NaN -> flag false
        bool fa = __uint_as_float(uE1[j] & 0xFFFFFFE0u) <= thr;
        bool fb = __uint_as_float(uE2[j] & 0xFFFFFFE0u) <= thr;
        bool fc = __uint_as_float(uO1[j] & 0xFFFFFFE0u) <= thr;
        bool fd = __uint_as_float(uO2[j] & 0xFFFFFFE0u) <= thr;
        unsigned long long ba = __ballot(fa);
        unsigned long long bb = __ballot(fb);
        unsigned long long bc = __ballot(fc);
        unsigned long long bd = __ballot(fd);
        unsigned fla = (unsigned)((ba >> (g * 16)) & 0xFFFFull);
        unsigned flb = (unsigned)((bb >> (g * 16)) & 0xFFFFull);
        unsigned flc = (unsigned)((bc >> (g * 16)) & 0xFFFFull);
        unsigned fld = (unsigned)((bd >> (g * 16)) & 0xFFFFull);
        const unsigned below = (1u << li) - 1u;
        int ca = __popc(fla), cb = __popc(flb), cc = __popc(flc);
        int pa = __popc(fla & below);
        int pb = ca + __popc(flb & below);
        int pc = ca + cb + __popc(flc & below);
        int pd = ca + cb + cc + __popc(fld & below);
        const int n_row = n_base + wv * 16 + g * 4 + j;
        if (fa && pa < MAXC) cand[n_row * MAXC + pa] = (unsigned short)((uE1[j] & 31u) * 32u + li);
        if (fb && pb < MAXC) cand[n_row * MAXC + pb] = (unsigned short)((uE2[j] & 31u) * 32u + li);
        if (fc && pc < MAXC) cand[n_row * MAXC + pc] = (unsigned short)((uO1[j] & 31u) * 32u + 16u + li);
        if (fd && pd < MAXC) cand[n_row * MAXC + pd] = (unsigned short)((uO2[j] & 31u) * 32u + 16u + li);
        if (li == 0) {
            int tot = ca + cb + cc + __popc(fld);
            cnt[n_row] = tot < MAXC ? tot : MAXC;
        }
    }
}

// ---- pass 3: exact f32 recheck of shortlist + gather + write + loss ----
__global__ __launch_bounds__(256) void vq_pick(
        const float* __restrict__ in, const float* __restrict__ emb,
        const float* __restrict__ ee, const unsigned short* __restrict__ cand,
        const int* __restrict__ cnt, float* __restrict__ out,
        float* __restrict__ partials) {
    const int n = blockIdx.x * 256 + threadIdx.x;
    const int w = n & 63;
    const int h = (n >> 6) & 63;
    const int b = n >> 12;
    const size_t base = ((size_t)b << 18) + ((size_t)h << 6) + (size_t)w;

    v2 x[32];
    #pragma unroll
    for (int d = 0; d < 32; ++d) {
        x[d].x = in[base + ((size_t)(2 * d + 0) << 12)];
        x[d].y = in[base + ((size_t)(2 * d + 1) << 12)];
    }
    asm volatile("" : "+v"(x[0]), "+v"(x[1]), "+v"(x[2]), "+v"(x[3]),
                      "+v"(x[4]), "+v"(x[5]), "+v"(x[6]), "+v"(x[7]),
                      "+v"(x[8]), "+v"(x[9]), "+v"(x[10]), "+v"(x[11]),
                      "+v"(x[12]), "+v"(x[13]), "+v"(x[14]), "+v"(x[15]));
    asm volatile("" : "+v"(x[16]), "+v"(x[17]), "+v"(x[18]), "+v"(x[19]),
                      "+v"(x[20]), "+v"(x[21]), "+v"(x[22]), "+v"(x[23]),
                      "+v"(x[24]), "+v"(x[25]), "+v"(x[26]), "+v"(x[27]),
                      "+v"(x[28]), "+v"(x[29]), "+v"(x[30]), "+v"(x[31]));

    // exact f32 distance for each shortlisted code -- bit-identical to R3's scan
    const int c0 = cnt[n];
    float bestD = 3.4e38f;
    int bestK = 0x7FFFFFFF;
    for (int s = 0; s < c0; ++s) {
        const int k = (int)cand[n * MAXC + s];
        const v2* __restrict__ e = (const v2*)(emb + (size_t)k * DIM);
        v2 a0 = {0.f, 0.f}, a1 = {0.f, 0.f}, a2 = {0.f, 0.f}, a3 = {0.f, 0.f};
        #pragma unroll
        for (int d = 0; d < 32; d += 4) {
            a0 = FMA2(x[d + 0], e[d + 0], a0);
            a1 = FMA2(x[d + 1], e[d + 1], a1);
            a2 = FMA2(x[d + 2], e[d + 2], a2);
            a3 = FMA2(x[d + 3], e[d + 3], a3);
        }
        v2 s2 = (a0 + a1) + (a2 + a3);
        float dk = fmaf(-2.f, s2.x + s2.y, ee[k]);
        // lexicographic (dist, k) min == ascending-k strict-< first occurrence
        if (dk < bestD || (dk == bestD && k < bestK)) { bestD = dk; bestK = k; }
    }
    out[OUT_Q + 1 + n] = (float)bestK;

    const v2* __restrict__ eq = (const v2*)(emb + (size_t)bestK * DIM);
    v2 errs2 = {0.f, 0.f};
    #pragma unroll
    for (int d = 0; d < 32; ++d) {
        v2 q = eq[d];
        v2 diff = q - x[d];
        errs2 = FMA2(diff, diff, errs2);
        out[base + ((size_t)(2 * d + 0) << 12)] = q.x;
        out[base + ((size_t)(2 * d + 1) << 12)] = q.y;
    }
    float errs = errs2.x + errs2.y;

    #pragma unroll
    for (int off = 32; off > 0; off >>= 1) errs += __shfl_xor(errs, off, 64);

    __shared__ float red[4];
    const int wave = threadIdx.x >> 6;
    const int lane = threadIdx.x & 63;
    if (lane == 0) red[wave] = errs;
    __syncthreads();
    if (threadIdx.x == 0) {
        partials[blockIdx.x] = (red[0] + red[1]) + (red[2] + red[3]);
    }
}

// ---- pass 4: deterministic final loss reduction ----
__global__ void vq_loss(const float* __restrict__ partials, float* __restrict__ out) {
    if (threadIdx.x == 0 && blockIdx.x == 0) {
        float s = 0.f;
        for (int i = 0; i < 512; ++i) s += partials[i];
        out[OUT_Q] = s * (float)(1.25 / 8388608.0);  // q_loss + 0.25*e_loss
    }
}

extern "C" void kernel_launch(void* const* d_in, const int* in_sizes, int n_in,
                              void* d_out, int out_size, void* d_ws, size_t ws_size,
                              hipStream_t stream) {
    const float* in  = (const float*)d_in[0];   // [32,64,64,64] f32
    const float* emb = (const float*)d_in[1];   // [1024,64] f32
    float* out = (float*)d_out;

    // ws layout: ee f32[1024] | eeb f32[1024+32 pad] | Bpack u16[66*2048 pad] |
    //            cand u16[NPOS*12] | cnt i32[NPOS] | partials f32[512]
    char* w = (char*)d_ws;
    float* ee = (float*)w;                      w += K_CODES * 4;
    float* eeb = (float*)w;                     w += (K_CODES + 32) * 4;
    unsigned short* Bpack = (unsigned short*)w; w += (size_t)66 * 2048 * 2;
    unsigned short* cand = (unsigned short*)w;  w += (size_t)NPOS * MAXC * 2;
    int* cnt = (int*)w;                         w += (size_t)NPOS * 4;
    float* partials = (float*)w;

    vq_prep<<<4, 256, 0, stream>>>(emb, ee, eeb, Bpack);
    vq_dist_mfma<<<2048, 256, 0, stream>>>(in, Bpack, eeb, cand, cnt);
    vq_pick<<<512, 256, 0, stream>>>(in, emb, ee, cand, cnt, out, partials);
    vq_loss<<<1, 64, 0, stream>>>(partials, out);
}

// Round 8
// 106.593 us; speedup vs baseline: 2.7837x; 1.0114x over previous
//
#include <hip/hip_runtime.h>

#define K_CODES 1024
#define DIM 64
#define OUT_Q 8388608  // 32*64*64*64 quantized elems; loss at [OUT_Q]; indices at [OUT_Q+1..]
#define NPOS 131072
#define MAXC 12        // shortlist slots per position
#define EPS 4e-3f      // shortlist margin (>=5x worst-case pack+approx skew ~7e-4)
#define BIAS 32.0f     // makes packed distances positive (|2*dot| <= ~26 < 32)

typedef float v2 __attribute__((ext_vector_type(2)));
typedef float f32x4 __attribute__((ext_vector_type(4)));
typedef short bf16x8 __attribute__((ext_vector_type(8)));

#if __has_builtin(__builtin_elementwise_fma)
#define FMA2(a, b, c) __builtin_elementwise_fma((a), (b), (c))
#else
static __device__ inline v2 FMA2(v2 a, v2 b, v2 c) {
    v2 r; r.x = fmaf(a.x, b.x, c.x); r.y = fmaf(a.y, b.y, c.y); return r;
}
#endif

static __device__ inline unsigned short f2bf(float f) {  // RNE f32->bf16
    union { float f; unsigned u; } c; c.f = f;
    unsigned u = c.u;
    u += 0x7fffu + ((u >> 16) & 1u);
    return (unsigned short)(u >> 16);
}
static __device__ inline float bf2f(unsigned short h) {
    union { unsigned u; float f; } c; c.u = ((unsigned)h) << 16;
    return c.f;
}

// ---- pass 1: exact ee[k], biased eeb[k], prepacked B fragments ----
// Bpack[kt][chunk][lane][j]: chunk 0/1 = hi half0/half1, chunk 2/3 = lo half0/half1.
// B-frag layout for mfma_16x16x32: lane l supplies B[kdim=(l>>4)*8+j][col=l&15].
__global__ void vq_prep(const float* __restrict__ emb, float* __restrict__ ee,
                        float* __restrict__ eeb, unsigned short* __restrict__ Bpack) {
    int k = blockIdx.x * blockDim.x + threadIdx.x;
    if (k < K_CODES) {
        const int kt = k >> 4, col = k & 15;
        float s = 0.f;
        #pragma unroll
        for (int d = 0; d < DIM; ++d) {
            float vv = emb[k * DIM + d];
            s = fmaf(vv, vv, s);
            unsigned short hh = f2bf(vv);
            unsigned short ll = f2bf(vv - bf2f(hh));
            const int half = d >> 5;
            const int lane = ((d >> 3) & 3) * 16 + col;
            const int j = d & 7;
            Bpack[kt * 2048 + half * 512 + lane * 8 + j] = hh;
            Bpack[kt * 2048 + (2 + half) * 512 + lane * 8 + j] = ll;
        }
        ee[k] = s;          // exact (recheck path)
        eeb[k] = s + BIAS;  // biased (approx path)
    }
}

// one 16x16 position-tile vs one 16-code tile: two 3-chains + packed best-2
#define PTILE(XH0, XL0, XH1, XL1, BH0, BH1, BL0, BL1, EEC, IDX, U1, U2)          \
    {                                                                            \
        f32x4 z = {0.f, 0.f, 0.f, 0.f};                                          \
        f32x4 p = __builtin_amdgcn_mfma_f32_16x16x32_bf16(XH0, BH0, z, 0, 0, 0); \
        p = __builtin_amdgcn_mfma_f32_16x16x32_bf16(XH0, BL0, p, 0, 0, 0);       \
        p = __builtin_amdgcn_mfma_f32_16x16x32_bf16(XL0, BH0, p, 0, 0, 0);       \
        f32x4 q = __builtin_amdgcn_mfma_f32_16x16x32_bf16(XH1, BH1, z, 0, 0, 0); \
        q = __builtin_amdgcn_mfma_f32_16x16x32_bf16(XH1, BL1, q, 0, 0, 0);       \
        q = __builtin_amdgcn_mfma_f32_16x16x32_bf16(XL1, BH1, q, 0, 0, 0);       \
        _Pragma("unroll")                                                        \
        for (int j = 0; j < 4; ++j) {                                            \
            float dd = fmaf(-2.f, p[j] + q[j], EEC);                             \
            unsigned uu = (__float_as_uint(dd) & 0xFFFFFFE0u) | (IDX);           \
            bool lt1 = uu < U1[j];                                               \
            unsigned t2 = uu < U2[j] ? uu : U2[j];                               \
            U2[j] = lt1 ? U1[j] : t2;                                            \
            U1[j] = lt1 ? uu : U1[j];                                            \
        }                                                                        \
    }

// shortlist emit for one position-tile's (E1,E2,O1,O2) candidate sets
#define EMIT(U_E1, U_E2, U_O1, U_O2, PBASE)                                                          \
    {                                                                                                \
        _Pragma("unroll")                                                                            \
        for (int j = 0; j < 4; ++j) {                                                                \
            unsigned um = U_E1[j] < U_O1[j] ? U_E1[j] : U_O1[j];                                     \
            _Pragma("unroll")                                                                        \
            for (int m = 1; m < 16; m <<= 1) {                                                       \
                unsigned o = (unsigned)__shfl_xor((int)um, m, 64);                                   \
                um = um < o ? um : o;                                                                \
            }                                                                                        \
            const float thr = __uint_as_float(um & 0xFFFFFFE0u) + EPS;                               \
            bool fa = __uint_as_float(U_E1[j] & 0xFFFFFFE0u) <= thr;                                 \
            bool fb = __uint_as_float(U_E2[j] & 0xFFFFFFE0u) <= thr;                                 \
            bool fc = __uint_as_float(U_O1[j] & 0xFFFFFFE0u) <= thr;                                 \
            bool fd = __uint_as_float(U_O2[j] & 0xFFFFFFE0u) <= thr;                                 \
            unsigned long long ba = __ballot(fa);                                                    \
            unsigned long long bb = __ballot(fb);                                                    \
            unsigned long long bc = __ballot(fc);                                                    \
            unsigned long long bd = __ballot(fd);                                                    \
            unsigned fla = (unsigned)((ba >> (g * 16)) & 0xFFFFull);                                 \
            unsigned flb = (unsigned)((bb >> (g * 16)) & 0xFFFFull);                                 \
            unsigned flc = (unsigned)((bc >> (g * 16)) & 0xFFFFull);                                 \
            unsigned fld = (unsigned)((bd >> (g * 16)) & 0xFFFFull);                                 \
            const unsigned below = (1u << li) - 1u;                                                  \
            int ca = __popc(fla), cb = __popc(flb), cc = __popc(flc);                                \
            int pa = __popc(fla & below);                                                            \
            int pb = ca + __popc(flb & below);                                                       \
            int pc = ca + cb + __popc(flc & below);                                                  \
            int pd = ca + cb + cc + __popc(fld & below);                                             \
            const int n_row = (PBASE) + g * 4 + j;                                                   \
            if (fa && pa < MAXC) cand[n_row * MAXC + pa] = (unsigned short)((U_E1[j] & 31u) * 32u + li);        \
            if (fb && pb < MAXC) cand[n_row * MAXC + pb] = (unsigned short)((U_E2[j] & 31u) * 32u + li);        \
            if (fc && pc < MAXC) cand[n_row * MAXC + pc] = (unsigned short)((U_O1[j] & 31u) * 32u + 16u + li);  \
            if (fd && pd < MAXC) cand[n_row * MAXC + pd] = (unsigned short)((U_O2[j] & 31u) * 32u + 16u + li);  \
            if (li == 0) {                                                                           \
                int tot = ca + cb + cc + __popc(fld);                                                \
                cnt[n_row] = tot < MAXC ? tot : MAXC;                                                \
            }                                                                                        \
        }                                                                                            \
    }

// ---- pass 2: MFMA approx distances, 32 positions (2 A-tiles) per wave ----
__global__ __launch_bounds__(256, 4) void vq_dist_mfma(
        const float* __restrict__ in, const unsigned short* __restrict__ Bpack,
        const float* __restrict__ eeb,
        unsigned short* __restrict__ cand, int* __restrict__ cnt) {
    const int t = threadIdx.x;
    const int wv = t >> 6;
    const int l = t & 63;
    const int li = l & 15;
    const int g = l >> 4;
    const int n_base = blockIdx.x * 128;  // 128 positions per block (never crosses b)
    const int b = n_base >> 12;
    const int o = n_base & 4095;
    const size_t ibase = ((size_t)b << 18) + (size_t)o;  // + d*4096 + pos

    // ---- A fragments: 2 position-tiles x 64 dims, hi/lo split, 2 K-halves ----
    // A layout (16x16x32): row = l&15, kdim = (l>>4)*8 + j
    const int dbase = g * 8;
    const int pos0 = wv * 32 + li;        // tile P0 rows
    const int pos1 = wv * 32 + 16 + li;   // tile P1 rows
    bf16x8 XAH0, XAL0, XAH1, XAL1, XBH0, XBL0, XBH1, XBL1;
    #pragma unroll
    for (int j = 0; j < 8; ++j) {
        float a0 = in[ibase + ((size_t)(dbase + j) << 12) + pos0];
        float a1 = in[ibase + ((size_t)(32 + dbase + j) << 12) + pos0];
        float b0 = in[ibase + ((size_t)(dbase + j) << 12) + pos1];
        float b1 = in[ibase + ((size_t)(32 + dbase + j) << 12) + pos1];
        unsigned short ah0 = f2bf(a0), ah1 = f2bf(a1), bh0 = f2bf(b0), bh1 = f2bf(b1);
        XAH0[j] = (short)ah0; XAL0[j] = (short)f2bf(a0 - bf2f(ah0));
        XAH1[j] = (short)ah1; XAL1[j] = (short)f2bf(a1 - bf2f(ah1));
        XBH0[j] = (short)bh0; XBL0[j] = (short)f2bf(b0 - bf2f(bh0));
        XBH1[j] = (short)bh1; XBL1[j] = (short)f2bf(b1 - bf2f(bh1));
    }
    asm volatile("" : "+v"(XAH0), "+v"(XAL0), "+v"(XAH1), "+v"(XAL1));
    asm volatile("" : "+v"(XBH0), "+v"(XBL0), "+v"(XBH1), "+v"(XBL1));

    unsigned uAE1[4], uAE2[4], uAO1[4], uAO2[4];
    unsigned uBE1[4], uBE2[4], uBO1[4], uBO2[4];
    #pragma unroll
    for (int j = 0; j < 4; ++j) {
        uAE1[j] = uAE2[j] = uAO1[j] = uAO2[j] = 0xFFFFFFFFu;
        uBE1[j] = uBE2[j] = uBO1[j] = uBO2[j] = 0xFFFFFFFFu;
    }

    // coalesced per-lane stream base (lane l's 16B at +l*16 within each 1KB chunk)
    const unsigned short* bp = Bpack + (size_t)l * 8;

    // preload tile 0 into B-reg set A
    bf16x8 h0A = *(const bf16x8*)(bp + 0);
    bf16x8 h1A = *(const bf16x8*)(bp + 512);
    bf16x8 l0A = *(const bf16x8*)(bp + 1024);
    bf16x8 l1A = *(const bf16x8*)(bp + 1536);
    float eA = eeb[li];
    unsigned cE = 0, cO = 0;  // class-local tile index (5 bits)

    for (int kt = 0; kt < 64; kt += 2) {
        // prefetch odd tile into B-reg set B
        const unsigned short* p1 = bp + (size_t)(kt + 1) * 2048;
        bf16x8 h0B = *(const bf16x8*)(p1 + 0);
        bf16x8 h1B = *(const bf16x8*)(p1 + 512);
        bf16x8 l0B = *(const bf16x8*)(p1 + 1024);
        bf16x8 l1B = *(const bf16x8*)(p1 + 1536);
        float eB = eeb[(kt + 1) * 16 + li];

        PTILE(XAH0, XAL0, XAH1, XAL1, h0A, h1A, l0A, l1A, eA, cE, uAE1, uAE2);
        PTILE(XBH0, XBL0, XBH1, XBL1, h0A, h1A, l0A, l1A, eA, cE, uBE1, uBE2);
        ++cE;

        // prefetch next even tile into B-reg set A (Bpack/eeb padded: safe at kt=62)
        const unsigned short* p2 = bp + (size_t)(kt + 2) * 2048;
        h0A = *(const bf16x8*)(p2 + 0);
        h1A = *(const bf16x8*)(p2 + 512);
        l0A = *(const bf16x8*)(p2 + 1024);
        l1A = *(const bf16x8*)(p2 + 1536);
        eA = eeb[(kt + 2) * 16 + li];

        PTILE(XAH0, XAL0, XAH1, XAL1, h0B, h1B, l0B, l1B, eB, cO, uAO1, uAO2);
        PTILE(XBH0, XBL0, XBH1, XBL1, h0B, h1B, l0B, l1B, eB, cO, uBO1, uBO2);
        ++cO;
    }

    // ---- shortlist: candidates within EPS of each row's approx min ----
    // k reconstruction: even class k = idx*32 + li ; odd class k = idx*32 + 16 + li
    EMIT(uAE1, uAE2, uAO1, uAO2, n_base + wv * 32);
    EMIT(uBE1, uBE2, uBO1, uBO2, n_base + wv * 32 + 16);
}

// ---- pass 3: exact f32 recheck of shortlist + gather + write + loss ----
__global__ __launch_bounds__(256) void vq_pick(
        const float* __restrict__ in, const float* __restrict__ emb,
        const float* __restrict__ ee, const unsigned short* __restrict__ cand,
        const int* __restrict__ cnt, float* __restrict__ out,
        float* __restrict__ partials) {
    const int n = blockIdx.x * 256 + threadIdx.x;
    const int w = n & 63;
    const int h = (n >> 6) & 63;
    const int b = n >> 12;
    const size_t base = ((size_t)b << 18) + ((size_t)h << 6) + (size_t)w;

    v2 x[32];
    #pragma unroll
    for (int d = 0; d < 32; ++d) {
        x[d].x = in[base + ((size_t)(2 * d + 0) << 12)];
        x[d].y = in[base + ((size_t)(2 * d + 1) << 12)];
    }
    asm volatile("" : "+v"(x[0]), "+v"(x[1]), "+v"(x[2]), "+v"(x[3]),
                      "+v"(x[4]), "+v"(x[5]), "+v"(x[6]), "+v"(x[7]),
                      "+v"(x[8]), "+v"(x[9]), "+v"(x[10]), "+v"(x[11]),
                      "+v"(x[12]), "+v"(x[13]), "+v"(x[14]), "+v"(x[15]));
    asm volatile("" : "+v"(x[16]), "+v"(x[17]), "+v"(x[18]), "+v"(x[19]),
                      "+v"(x[20]), "+v"(x[21]), "+v"(x[22]), "+v"(x[23]),
                      "+v"(x[24]), "+v"(x[25]), "+v"(x[26]), "+v"(x[27]),
                      "+v"(x[28]), "+v"(x[29]), "+v"(x[30]), "+v"(x[31]));

    // exact f32 distance for each shortlisted code -- bit-identical to R3's scan
    const int c0 = cnt[n];
    float bestD = 3.4e38f;
    int bestK = 0x7FFFFFFF;
    for (int s = 0; s < c0; ++s) {
        const int k = (int)cand[n * MAXC + s];
        const v2* __restrict__ e = (const v2*)(emb + (size_t)k * DIM);
        v2 a0 = {0.f, 0.f}, a1 = {0.f, 0.f}, a2 = {0.f, 0.f}, a3 = {0.f, 0.f};
        #pragma unroll
        for (int d = 0; d < 32; d += 4) {
            a0 = FMA2(x[d + 0], e[d + 0], a0);
            a1 = FMA2(x[d + 1], e[d + 1], a1);
            a2 = FMA2(x[d + 2], e[d + 2], a2);
            a3 = FMA2(x[d + 3], e[d + 3], a3);
        }
        v2 s2 = (a0 + a1) + (a2 + a3);
        float dk = fmaf(-2.f, s2.x + s2.y, ee[k]);
        // lexicographic (dist, k) min == ascending-k strict-< first occurrence
        if (dk < bestD || (dk == bestD && k < bestK)) { bestD = dk; bestK = k; }
    }
    out[OUT_Q + 1 + n] = (float)bestK;

    const v2* __restrict__ eq = (const v2*)(emb + (size_t)bestK * DIM);
    v2 errs2 = {0.f, 0.f};
    #pragma unroll
    for (int d = 0; d < 32; ++d) {
        v2 q = eq[d];
        v2 diff = q - x[d];
        errs2 = FMA2(diff, diff, errs2);
        out[base + ((size_t)(2 * d + 0) << 12)] = q.x;
        out[base + ((size_t)(2 * d + 1) << 12)] = q.y;
    }
    float errs = errs2.x + errs2.y;

    #pragma unroll
    for (int off = 32; off > 0; off >>= 1) errs += __shfl_xor(errs, off, 64);

    __shared__ float red[4];
    const int wave = threadIdx.x >> 6;
    const int lane = threadIdx.x & 63;
    if (lane == 0) red[wave] = errs;
    __syncthreads();
    if (threadIdx.x == 0) {
        partials[blockIdx.x] = (red[0] + red[1]) + (red[2] + red[3]);
    }
}

// ---- pass 4: deterministic final loss reduction ----
__global__ void vq_loss(const float* __restrict__ partials, float* __restrict__ out) {
    if (threadIdx.x == 0 && blockIdx.x == 0) {
        float s = 0.f;
        for (int i = 0; i < 512; ++i) s += partials[i];
        out[OUT_Q] = s * (float)(1.25 / 8388608.0);  // q_loss + 0.25*e_loss
    }
}

extern "C" void kernel_launch(void* const* d_in, const int* in_sizes, int n_in,
                              void* d_out, int out_size, void* d_ws, size_t ws_size,
                              hipStream_t stream) {
    const float* in  = (const float*)d_in[0];   // [32,64,64,64] f32
    const float* emb = (const float*)d_in[1];   // [1024,64] f32
    float* out = (float*)d_out;

    // ws layout: ee f32[1024] | eeb f32[1024+32 pad] | Bpack u16[66*2048 pad] |
    //            cand u16[NPOS*12] | cnt i32[NPOS] | partials f32[512]
    char* w = (char*)d_ws;
    float* ee = (float*)w;                      w += K_CODES * 4;
    float* eeb = (float*)w;                     w += (K_CODES + 32) * 4;
    unsigned short* Bpack = (unsigned short*)w; w += (size_t)66 * 2048 * 2;
    unsigned short* cand = (unsigned short*)w;  w += (size_t)NPOS * MAXC * 2;
    int* cnt = (int*)w;                         w += (size_t)NPOS * 4;
    float* partials = (float*)w;

    vq_prep<<<4, 256, 0, stream>>>(emb, ee, eeb, Bpack);
    vq_dist_mfma<<<1024, 256, 0, stream>>>(in, Bpack, eeb, cand, cnt);
    vq_pick<<<512, 256, 0, stream>>>(in, emb, ee, cand, cnt, out, partials);
    vq_loss<<<1, 64, 0, stream>>>(partials, out);
}

// Round 9
// 93.916 us; speedup vs baseline: 3.1594x; 1.1350x over previous
//
#include <hip/hip_runtime.h>

#define K_CODES 1024
#define DIM 64
#define OUT_Q 8388608  // 32*64*64*64 quantized elems; loss at [OUT_Q]; indices at [OUT_Q+1..]
#define NPOS 131072
#define MAXC 12        // shortlist slots per position
#define EPS 4e-3f      // shortlist margin (>=5x worst-case pack+approx skew ~7e-4)
#define BIAS 32.0f     // makes packed distances positive (|2*dot| <= ~26 < 32)

typedef float v2 __attribute__((ext_vector_type(2)));
typedef float f32x4 __attribute__((ext_vector_type(4)));
typedef short bf16x8 __attribute__((ext_vector_type(8)));
typedef unsigned int u32;
#define GLOBAL_AS __attribute__((address_space(1)))
#define LDS_AS __attribute__((address_space(3)))

#if __has_builtin(__builtin_elementwise_fma)
#define FMA2(a, b, c) __builtin_elementwise_fma((a), (b), (c))
#else
static __device__ inline v2 FMA2(v2 a, v2 b, v2 c) {
    v2 r; r.x = fmaf(a.x, b.x, c.x); r.y = fmaf(a.y, b.y, c.y); return r;
}
#endif

static __device__ inline unsigned short f2bf(float f) {  // RNE f32->bf16
    union { float f; unsigned u; } c; c.f = f;
    unsigned u = c.u;
    u += 0x7fffu + ((u >> 16) & 1u);
    return (unsigned short)(u >> 16);
}
static __device__ inline float bf2f(unsigned short h) {
    union { unsigned u; float f; } c; c.u = ((unsigned)h) << 16;
    return c.f;
}

// ---- pass 1: exact ee[k], biased eeb[k], prepacked B fragments ----
// Bpack[kt][chunk][lane][j]: chunk 0/1 = hi half0/half1, chunk 2/3 = lo half0/half1.
// B-frag layout for mfma_16x16x32: lane l supplies B[kdim=(l>>4)*8+j][col=l&15].
__global__ void vq_prep(const float* __restrict__ emb, float* __restrict__ ee,
                        float* __restrict__ eeb, unsigned short* __restrict__ Bpack) {
    int k = blockIdx.x * blockDim.x + threadIdx.x;
    if (k < K_CODES) {
        const int kt = k >> 4, col = k & 15;
        float s = 0.f;
        #pragma unroll
        for (int d = 0; d < DIM; ++d) {
            float vv = emb[k * DIM + d];
            s = fmaf(vv, vv, s);
            unsigned short hh = f2bf(vv);
            unsigned short ll = f2bf(vv - bf2f(hh));
            const int half = d >> 5;
            const int lane = ((d >> 3) & 3) * 16 + col;
            const int j = d & 7;
            Bpack[kt * 2048 + half * 512 + lane * 8 + j] = hh;
            Bpack[kt * 2048 + (2 + half) * 512 + lane * 8 + j] = ll;
        }
        ee[k] = s;          // exact (recheck path)
        eeb[k] = s + BIAS;  // biased (approx path)
    }
}

// one 16x16 position-tile vs one 16-code tile: two 3-chains + 3-op packed best-2
#define PTILE(XH0, XL0, XH1, XL1, BH0, BH1, BL0, BL1, EEC, IDX, U1, U2)          \
    {                                                                            \
        f32x4 z = {0.f, 0.f, 0.f, 0.f};                                          \
        f32x4 p = __builtin_amdgcn_mfma_f32_16x16x32_bf16(XH0, BH0, z, 0, 0, 0); \
        p = __builtin_amdgcn_mfma_f32_16x16x32_bf16(XH0, BL0, p, 0, 0, 0);       \
        p = __builtin_amdgcn_mfma_f32_16x16x32_bf16(XL0, BH0, p, 0, 0, 0);       \
        f32x4 q = __builtin_amdgcn_mfma_f32_16x16x32_bf16(XH1, BH1, z, 0, 0, 0); \
        q = __builtin_amdgcn_mfma_f32_16x16x32_bf16(XH1, BL1, q, 0, 0, 0);       \
        q = __builtin_amdgcn_mfma_f32_16x16x32_bf16(XL1, BH1, q, 0, 0, 0);       \
        _Pragma("unroll")                                                        \
        for (int j = 0; j < 4; ++j) {                                            \
            float dd = fmaf(-2.f, p[j] + q[j], EEC);                             \
            unsigned uu = (__float_as_uint(dd) & 0xFFFFFFE0u) | (IDX);           \
            unsigned mn = uu < U2[j] ? uu : U2[j];          /* v_min_u32 */      \
            U2[j] = U1[j] > mn ? U1[j] : mn;                /* v_max_u32 */      \
            U1[j] = uu < U1[j] ? uu : U1[j];                /* v_min_u32 */      \
        }                                                                        \
    }

// shortlist emit for one position-tile's (E1,E2,O1,O2) candidate sets
#define EMIT(U_E1, U_E2, U_O1, U_O2, PBASE)                                                          \
    {                                                                                                \
        _Pragma("unroll")                                                                            \
        for (int j = 0; j < 4; ++j) {                                                                \
            unsigned um = U_E1[j] < U_O1[j] ? U_E1[j] : U_O1[j];                                     \
            _Pragma("unroll")                                                                        \
            for (int m = 1; m < 16; m <<= 1) {                                                       \
                unsigned o = (unsigned)__shfl_xor((int)um, m, 64);                                   \
                um = um < o ? um : o;                                                                \
            }                                                                                        \
            const float thr = __uint_as_float(um & 0xFFFFFFE0u) + EPS;                               \
            bool fa = __uint_as_float(U_E1[j] & 0xFFFFFFE0u) <= thr;                                 \
            bool fb = __uint_as_float(U_E2[j] & 0xFFFFFFE0u) <= thr;                                 \
            bool fc = __uint_as_float(U_O1[j] & 0xFFFFFFE0u) <= thr;                                 \
            bool fd = __uint_as_float(U_O2[j] & 0xFFFFFFE0u) <= thr;                                 \
            unsigned long long ba = __ballot(fa);                                                    \
            unsigned long long bb = __ballot(fb);                                                    \
            unsigned long long bc = __ballot(fc);                                                    \
            unsigned long long bd = __ballot(fd);                                                    \
            unsigned fla = (unsigned)((ba >> (g * 16)) & 0xFFFFull);                                 \
            unsigned flb = (unsigned)((bb >> (g * 16)) & 0xFFFFull);                                 \
            unsigned flc = (unsigned)((bc >> (g * 16)) & 0xFFFFull);                                 \
            unsigned fld = (unsigned)((bd >> (g * 16)) & 0xFFFFull);                                 \
            const unsigned below = (1u << li) - 1u;                                                  \
            int ca = __popc(fla), cb = __popc(flb), cc = __popc(flc);                                \
            int pa = __popc(fla & below);                                                            \
            int pb = ca + __popc(flb & below);                                                       \
            int pc = ca + cb + __popc(flc & below);                                                  \
            int pd = ca + cb + cc + __popc(fld & below);                                             \
            const int n_row = (PBASE) + g * 4 + j;                                                   \
            if (fa && pa < MAXC) cand[n_row * MAXC + pa] = (unsigned short)((U_E1[j] & 31u) * 32u + li);        \
            if (fb && pb < MAXC) cand[n_row * MAXC + pb] = (unsigned short)((U_E2[j] & 31u) * 32u + li);        \
            if (fc && pc < MAXC) cand[n_row * MAXC + pc] = (unsigned short)((U_O1[j] & 31u) * 32u + 16u + li);  \
            if (fd && pd < MAXC) cand[n_row * MAXC + pd] = (unsigned short)((U_O2[j] & 31u) * 32u + 16u + li);  \
            if (li == 0) {                                                                           \
                int tot = ca + cb + cc + __popc(fld);                                                \
                cnt[n_row] = tot < MAXC ? tot : MAXC;                                                \
            }                                                                                        \
        }                                                                                            \
    }

// stage one 16-code tile's 4KB into an LDS slot: each wave DMAs its 1KB chunk
#define STAGE(tile, slot)                                                               \
    __builtin_amdgcn_global_load_lds(                                                   \
        (const GLOBAL_AS u32*)(Bpack + (size_t)(tile) * 2048 + wv * 512 + l * 8),       \
        (LDS_AS u32*)(&ldsB[(slot) * 2048 + wv * 512]), 16, 0, 0)

// ---- pass 2: MFMA approx distances, 32 positions/wave, LDS-shared B stream ----
__global__ __launch_bounds__(256, 4) void vq_dist_mfma(
        const float* __restrict__ in, const unsigned short* __restrict__ Bpack,
        const float* __restrict__ eeb,
        unsigned short* __restrict__ cand, int* __restrict__ cnt) {
    __shared__ unsigned short ldsB[6 * 2048];  // 3 pair-slots x 2 tiles x 4KB = 24KB
    const int t = threadIdx.x;
    const int wv = t >> 6;
    const int l = t & 63;
    const int li = l & 15;
    const int g = l >> 4;
    const int n_base = blockIdx.x * 128;  // 128 positions per block (never crosses b)
    const size_t ibase = ((size_t)(n_base >> 12) << 18) + (size_t)(n_base & 4095);

    // prologue: stage tiles 0..3 into pair-slots 0,1
    STAGE(0, 0); STAGE(1, 1); STAGE(2, 2); STAGE(3, 3);

    // ---- A fragments: 2 position-tiles x 64 dims, hi/lo split, 2 K-halves ----
    // A layout (16x16x32): row = l&15, kdim = (l>>4)*8 + j
    const int dbase = g * 8;
    const int pos0 = wv * 32 + li;        // tile P0 rows
    const int pos1 = wv * 32 + 16 + li;   // tile P1 rows
    bf16x8 XAH0, XAL0, XAH1, XAL1, XBH0, XBL0, XBH1, XBL1;
    #pragma unroll
    for (int j = 0; j < 8; ++j) {
        float a0 = in[ibase + ((size_t)(dbase + j) << 12) + pos0];
        float a1 = in[ibase + ((size_t)(32 + dbase + j) << 12) + pos0];
        float b0 = in[ibase + ((size_t)(dbase + j) << 12) + pos1];
        float b1 = in[ibase + ((size_t)(32 + dbase + j) << 12) + pos1];
        unsigned short ah0 = f2bf(a0), ah1 = f2bf(a1), bh0 = f2bf(b0), bh1 = f2bf(b1);
        XAH0[j] = (short)ah0; XAL0[j] = (short)f2bf(a0 - bf2f(ah0));
        XAH1[j] = (short)ah1; XAL1[j] = (short)f2bf(a1 - bf2f(ah1));
        XBH0[j] = (short)bh0; XBL0[j] = (short)f2bf(b0 - bf2f(bh0));
        XBH1[j] = (short)bh1; XBL1[j] = (short)f2bf(b1 - bf2f(bh1));
    }
    asm volatile("" : "+v"(XAH0), "+v"(XAL0), "+v"(XAH1), "+v"(XAL1));
    asm volatile("" : "+v"(XBH0), "+v"(XBL0), "+v"(XBH1), "+v"(XBL1));

    unsigned uAE1[4], uAE2[4], uAO1[4], uAO2[4];
    unsigned uBE1[4], uBE2[4], uBO1[4], uBO2[4];
    #pragma unroll
    for (int j = 0; j < 4; ++j) {
        uAE1[j] = uAE2[j] = uAO1[j] = uAO2[j] = 0xFFFFFFFFu;
        uBE1[j] = uBE2[j] = uBO1[j] = uBO2[j] = 0xFFFFFFFFu;
    }

    unsigned cE = 0, cO = 0;  // class-local tile index (5 bits)
    __syncthreads();          // prologue staging visible

    for (int kt = 0; kt < 64; kt += 2) {
        const int ps = (kt >> 1) % 3;
        // stage pair (kt+4, kt+5) into pair-slot (ps+2)%3 -- last read 2 barriers ago
        if (kt < 60) {
            const int ps2 = (ps + 2) % 3;
            STAGE(kt + 4, 2 * ps2);
            STAGE(kt + 5, 2 * ps2 + 1);
        }
        // even tile kt from slot 2*ps
        {
            const unsigned short* lp = &ldsB[(2 * ps) * 2048] + l * 8;
            bf16x8 h0 = *(const bf16x8*)(lp + 0);
            bf16x8 h1 = *(const bf16x8*)(lp + 512);
            bf16x8 l0 = *(const bf16x8*)(lp + 1024);
            bf16x8 l1 = *(const bf16x8*)(lp + 1536);
            float eE = eeb[kt * 16 + li];
            PTILE(XAH0, XAL0, XAH1, XAL1, h0, h1, l0, l1, eE, cE, uAE1, uAE2);
            PTILE(XBH0, XBL0, XBH1, XBL1, h0, h1, l0, l1, eE, cE, uBE1, uBE2);
            ++cE;
        }
        // odd tile kt+1 from slot 2*ps+1
        {
            const unsigned short* lp = &ldsB[(2 * ps + 1) * 2048] + l * 8;
            bf16x8 h0 = *(const bf16x8*)(lp + 0);
            bf16x8 h1 = *(const bf16x8*)(lp + 512);
            bf16x8 l0 = *(const bf16x8*)(lp + 1024);
            bf16x8 l1 = *(const bf16x8*)(lp + 1536);
            float eO = eeb[(kt + 1) * 16 + li];
            PTILE(XAH0, XAL0, XAH1, XAL1, h0, h1, l0, l1, eO, cO, uAO1, uAO2);
            PTILE(XBH0, XBL0, XBH1, XBL1, h0, h1, l0, l1, eO, cO, uBO1, uBO2);
            ++cO;
        }
        __syncthreads();
    }

    // ---- shortlist: candidates within EPS of each row's approx min ----
    // k reconstruction: even class k = idx*32 + li ; odd class k = idx*32 + 16 + li
    EMIT(uAE1, uAE2, uAO1, uAO2, n_base + wv * 32);
    EMIT(uBE1, uBE2, uBO1, uBO2, n_base + wv * 32 + 16);
}

// ---- pass 3: exact f32 recheck of shortlist + gather + write + loss ----
__global__ __launch_bounds__(256) void vq_pick(
        const float* __restrict__ in, const float* __restrict__ emb,
        const float* __restrict__ ee, const unsigned short* __restrict__ cand,
        const int* __restrict__ cnt, float* __restrict__ out,
        float* __restrict__ partials) {
    const int n = blockIdx.x * 256 + threadIdx.x;
    const int w = n & 63;
    const int h = (n >> 6) & 63;
    const int b = n >> 12;
    const size_t base = ((size_t)b << 18) + ((size_t)h << 6) + (size_t)w;

    v2 x[32];
    #pragma unroll
    for (int d = 0; d < 32; ++d) {
        x[d].x = in[base + ((size_t)(2 * d + 0) << 12)];
        x[d].y = in[base + ((size_t)(2 * d + 1) << 12)];
    }
    asm volatile("" : "+v"(x[0]), "+v"(x[1]), "+v"(x[2]), "+v"(x[3]),
                      "+v"(x[4]), "+v"(x[5]), "+v"(x[6]), "+v"(x[7]),
                      "+v"(x[8]), "+v"(x[9]), "+v"(x[10]), "+v"(x[11]),
                      "+v"(x[12]), "+v"(x[13]), "+v"(x[14]), "+v"(x[15]));
    asm volatile("" : "+v"(x[16]), "+v"(x[17]), "+v"(x[18]), "+v"(x[19]),
                      "+v"(x[20]), "+v"(x[21]), "+v"(x[22]), "+v"(x[23]),
                      "+v"(x[24]), "+v"(x[25]), "+v"(x[26]), "+v"(x[27]),
                      "+v"(x[28]), "+v"(x[29]), "+v"(x[30]), "+v"(x[31]));

    // exact f32 distance for each shortlisted code -- bit-identical to R3's scan
    const int c0 = cnt[n];
    float bestD = 3.4e38f;
    int bestK = 0x7FFFFFFF;
    for (int s = 0; s < c0; ++s) {
        const int k = (int)cand[n * MAXC + s];
        const v2* __restrict__ e = (const v2*)(emb + (size_t)k * DIM);
        v2 a0 = {0.f, 0.f}, a1 = {0.f, 0.f}, a2 = {0.f, 0.f}, a3 = {0.f, 0.f};
        #pragma unroll
        for (int d = 0; d < 32; d += 4) {
            a0 = FMA2(x[d + 0], e[d + 0], a0);
            a1 = FMA2(x[d + 1], e[d + 1], a1);
            a2 = FMA2(x[d + 2], e[d + 2], a2);
            a3 = FMA2(x[d + 3], e[d + 3], a3);
        }
        v2 s2 = (a0 + a1) + (a2 + a3);
        float dk = fmaf(-2.f, s2.x + s2.y, ee[k]);
        // lexicographic (dist, k) min == ascending-k strict-< first occurrence
        if (dk < bestD || (dk == bestD && k < bestK)) { bestD = dk; bestK = k; }
    }
    out[OUT_Q + 1 + n] = (float)bestK;

    const v2* __restrict__ eq = (const v2*)(emb + (size_t)bestK * DIM);
    v2 errs2 = {0.f, 0.f};
    #pragma unroll
    for (int d = 0; d < 32; ++d) {
        v2 q = eq[d];
        v2 diff = q - x[d];
        errs2 = FMA2(diff, diff, errs2);
        out[base + ((size_t)(2 * d + 0) << 12)] = q.x;
        out[base + ((size_t)(2 * d + 1) << 12)] = q.y;
    }
    float errs = errs2.x + errs2.y;

    #pragma unroll
    for (int off = 32; off > 0; off >>= 1) errs += __shfl_xor(errs, off, 64);

    __shared__ float red[4];
    const int wave = threadIdx.x >> 6;
    const int lane = threadIdx.x & 63;
    if (lane == 0) red[wave] = errs;
    __syncthreads();
    if (threadIdx.x == 0) {
        partials[blockIdx.x] = (red[0] + red[1]) + (red[2] + red[3]);
    }
}

// ---- pass 4: deterministic final loss reduction ----
__global__ void vq_loss(const float* __restrict__ partials, float* __restrict__ out) {
    if (threadIdx.x == 0 && blockIdx.x == 0) {
        float s = 0.f;
        for (int i = 0; i < 512; ++i) s += partials[i];
        out[OUT_Q] = s * (float)(1.25 / 8388608.0);  // q_loss + 0.25*e_loss
    }
}

extern "C" void kernel_launch(void* const* d_in, const int* in_sizes, int n_in,
                              void* d_out, int out_size, void* d_ws, size_t ws_size,
                              hipStream_t stream) {
    const float* in  = (const float*)d_in[0];   // [32,64,64,64] f32
    const float* emb = (const float*)d_in[1];   // [1024,64] f32
    float* out = (float*)d_out;

    // ws layout: ee f32[1024] | eeb f32[1024+32 pad] | Bpack u16[66*2048 pad] |
    //            cand u16[NPOS*12] | cnt i32[NPOS] | partials f32[512]
    char* w = (char*)d_ws;
    float* ee = (float*)w;                      w += K_CODES * 4;
    float* eeb = (float*)w;                     w += (K_CODES + 32) * 4;
    unsigned short* Bpack = (unsigned short*)w; w += (size_t)66 * 2048 * 2;
    unsigned short* cand = (unsigned short*)w;  w += (size_t)NPOS * MAXC * 2;
    int* cnt = (int*)w;                         w += (size_t)NPOS * 4;
    float* partials = (float*)w;

    vq_prep<<<4, 256, 0, stream>>>(emb, ee, eeb, Bpack);
    vq_dist_mfma<<<1024, 256, 0, stream>>>(in, Bpack, eeb, cand, cnt);
    vq_pick<<<512, 256, 0, stream>>>(in, emb, ee, cand, cnt, out, partials);
    vq_loss<<<1, 64, 0, stream>>>(partials, out);
}